// Round 2
// baseline (170.099 us; speedup 1.0000x reference)
//
#include <hip/hip_runtime.h>
#include <hip/hip_bf16.h>
#include <hip/hip_fp16.h>
#include <math.h>

// Problem constants
#define B_ 4
#define C_ 256
#define H_ 64
#define W_ 64
#define COMP_ 64
#define K2_ 25
#define HW_ (H_*W_)   // 4096
#define EPS_ 1e-5f
#define WTE_STRIDE 26  // 25 k2 values padded to 26 for 8B-aligned float2 loads

typedef float v2f __attribute__((ext_vector_type(2)));
#define FMA2(a, b, c) __builtin_elementwise_fma((a), (b), (c))

// Async global->LDS (size must be a literal). LDS dest = uniform base + lane*size.
__device__ __forceinline__ void gload4(const void* g, void* l) {
    __builtin_amdgcn_global_load_lds((const __attribute__((address_space(1))) void*)g,
                                     (__attribute__((address_space(3))) void*)l, 4, 0, 0);
}
__device__ __forceinline__ void gload16(const void* g, void* l) {
    __builtin_amdgcn_global_load_lds((const __attribute__((address_space(1))) void*)g,
                                     (__attribute__((address_space(3))) void*)l, 16, 0, 0);
}

// ---------------------------------------------------------------------------
// Kernel T: weight layout transforms (scalar-load-friendly).
//   wTc[c*64+o]                        = w_comp[o*256+c]
//   wTe[((o*9+q)*4+s2)*26 + k2]        = w_enc[((k2*4+s2)*64+o)*9+q]
// ---------------------------------------------------------------------------
__global__ void k_transpose(const float* __restrict__ w_comp,
                            const float* __restrict__ w_enc,
                            float* __restrict__ wTc,
                            float* __restrict__ wTe) {
    int t = blockIdx.x * 256 + threadIdx.x;
    if (t < COMP_ * C_) {
        int o = t & 63;
        int c = t >> 6;
        wTc[t] = w_comp[o * C_ + c];
    } else {
        int t2 = t - COMP_ * C_;
        if (t2 < 100 * COMP_ * 9) {
            int k2 = t2 % 25;
            int r = t2 / 25;
            int s2 = r & 3; r >>= 2;
            int q = r % 9;
            int o = r / 9;
            wTe[((o * 9 + q) * 4 + s2) * WTE_STRIDE + k2] =
                w_enc[(((k2 * 4 + s2) * COMP_) + o) * 9 + q];
        }
    }
}

// ---------------------------------------------------------------------------
// Kernel A (v2, unchanged): 1x1 compression (256->64) + BN + SiLU.
// ---------------------------------------------------------------------------
__global__ void __launch_bounds__(512)
k_compress(const float* __restrict__ x, const float* __restrict__ wTc,
           const float* __restrict__ gamma, const float* __restrict__ beta,
           const float* __restrict__ mean, const float* __restrict__ var,
           float* __restrict__ act) {
    __shared__ float sx[256 * 68];                 // 69,632 B
    const int tx = threadIdx.x;                    // px
    const int ty = threadIdx.y;                    // og (0..7)
    const int tid = ty * 64 + tx;
    const int ogu = __builtin_amdgcn_readfirstlane(ty);
    const int b = blockIdx.y;
    const int p0 = blockIdx.x * 64;

    const float* xb = x + (size_t)b * C_ * HW_ + p0;
#pragma unroll
    for (int l = 0; l < 8; ++l) {
        int e = tid + l * 512;                     // 0..4095
        int c = e >> 4;
        int p4 = (e & 15) << 2;
        float4 v4 = *(const float4*)(xb + (size_t)c * HW_ + p4);
        *(float4*)&sx[c * 68 + p4] = v4;
    }
    __syncthreads();

    v2f acc2[4];
#pragma unroll
    for (int k = 0; k < 4; ++k) acc2[k] = (v2f){0.f, 0.f};

#pragma unroll 8
    for (int c = 0; c < 256; ++c) {
        float xv = sx[c * 68 + tx];
        const v2f* w2 = (const v2f*)(wTc + c * COMP_ + ogu * 8);  // uniform -> s_load
        v2f xv2 = (v2f){xv, xv};
#pragma unroll
        for (int k = 0; k < 4; ++k)
            acc2[k] = FMA2(xv2, w2[k], acc2[k]);
    }

#pragma unroll
    for (int k = 0; k < 4; ++k) {
        int o0 = ty * 8 + 2 * k;
#pragma unroll
        for (int h = 0; h < 2; ++h) {
            int o = o0 + h;
            float sv = (h == 0) ? acc2[k].x : acc2[k].y;
            float iv = gamma[o] * rsqrtf(var[o] + EPS_);
            float bn = (sv - mean[o]) * iv + beta[o];
            float sg = 1.f / (1.f + __expf(-bn));
            act[((b * COMP_ + o) * HW_) + p0 + tx] = bn * sg;
        }
    }
}

// ---------------------------------------------------------------------------
// Kernel B (v2): 3x3 encoder conv (64->100) + softmax(25) + fp16 out.
// s2 split across grid: grid (64 i, 4 b, 2 s2h) = 512 blocks -> 2 blocks/CU
// (was 1 — zero inter-block overlap). Block (64 j, 2 s2loc, 4 og) = 512 thr.
// Per-thread work identical to v1; block latency halves; two independent
// blocks per CU cover each other's staging + reduction barriers.
// ---------------------------------------------------------------------------
__global__ void __launch_bounds__(512)
k_encoder(const float* __restrict__ act, const float* __restrict__ wTe,
          __half* __restrict__ maskT) {
    __shared__ float sact[13312];                  // 53.2 KB (reused: reduce bufs, st)
    const int tx = threadIdx.x;                    // j
    const int ty = threadIdx.y;                    // s2loc (0..1)
    const int tz = threadIdx.z;                    // og (0..3)
    const int tid = (tz * 2 + ty) * 64 + tx;
    const int i = blockIdx.x;
    const int b = blockIdx.y;
    const int s2h = blockIdx.z;
    const int s2u = __builtin_amdgcn_readfirstlane(s2h * 2 + ty);  // wave-uniform
    const int ogu = __builtin_amdgcn_readfirstlane(tz);

    // stage act rows i-1..i+1 with zero halo: [row][o][col(=gj+1)], 3*64*66
    const float* ab = act + (size_t)b * COMP_ * HW_;
    for (int t = tid; t < 3 * COMP_ * 66; t += 512) {
        int col = t % 66;
        int r = t / 66;
        int o = r & 63;
        int row = r >> 6;
        int gi = i + row - 1;
        int gj = col - 1;
        float v = 0.f;
        if ((unsigned)gi < 64u && (unsigned)gj < 64u)
            v = ab[(o * H_ + gi) * W_ + gj];
        sact[t] = v;
    }
    __syncthreads();

    v2f acc2[13];
#pragma unroll
    for (int k = 0; k < 13; ++k) acc2[k] = (v2f){0.f, 0.f};

#pragma unroll 2
    for (int oi = 0; oi < 16; ++oi) {
        int o = ogu * 16 + oi;                     // uniform
#pragma unroll
        for (int q = 0; q < 9; ++q) {
            const int dy = q / 3, dx = q % 3;
            float a = sact[(dy * COMP_ + o) * 66 + tx + dx];
            const float* wb = wTe + ((o * 9 + q) * 4 + s2u) * WTE_STRIDE;  // uniform
            const v2f* w2 = (const v2f*)wb;
            v2f a2 = (v2f){a, a};
#pragma unroll
            for (int k = 0; k < 12; ++k)
                acc2[k] = FMA2(a2, w2[k], acc2[k]);
            acc2[12].x = fmaf(wb[24], a, acc2[12].x);
        }
    }
    __syncthreads();                               // sact reads done

    v2f* bufA = (v2f*)sact;                        // 13*128 v2f
    v2f* bufB = bufA + 13 * 128;                   // 13*128 v2f
    const int rix = ty * 64 + tx;                  // 0..127
    if (tz == 1) {
#pragma unroll
        for (int k = 0; k < 13; ++k) bufA[k * 128 + rix] = acc2[k];
    } else if (tz == 2) {
#pragma unroll
        for (int k = 0; k < 13; ++k) bufB[k * 128 + rix] = acc2[k];
    }
    __syncthreads();
    if (tz == 0) {
#pragma unroll
        for (int k = 0; k < 13; ++k) acc2[k] += bufA[k * 128 + rix];
    } else if (tz == 3) {
#pragma unroll
        for (int k = 0; k < 13; ++k) acc2[k] += bufB[k * 128 + rix];
    }
    __syncthreads();
    if (tz == 3) {
#pragma unroll
        for (int k = 0; k < 13; ++k) bufA[k * 128 + rix] = acc2[k];
    }
    __syncthreads();
    float ex[K2_];
    if (tz == 0) {
#pragma unroll
        for (int k = 0; k < 13; ++k) acc2[k] += bufA[k * 128 + rix];

        // softmax over 25 (acc2[12].y is junk — ignored)
        float mx = acc2[12].x;
#pragma unroll
        for (int k = 0; k < 12; ++k) mx = fmaxf(mx, fmaxf(acc2[k].x, acc2[k].y));
        float sum = 0.f;
#pragma unroll
        for (int k = 0; k < 12; ++k) {
            ex[2 * k]     = __expf(acc2[k].x - mx);
            ex[2 * k + 1] = __expf(acc2[k].y - mx);
            sum += ex[2 * k] + ex[2 * k + 1];
        }
        ex[24] = __expf(acc2[12].x - mx);
        sum += ex[24];
        float rs = 1.f / sum;
#pragma unroll
        for (int k = 0; k < K2_; ++k) ex[k] *= rs;
    }
    __syncthreads();                               // bufA reads done before st reuse

    // st[j][50(+2 pad)] halfs: (k2, s2loc) interleave for half2 global stores
    __half* st = (__half*)sact;
    if (tz == 0) {
#pragma unroll
        for (int k = 0; k < K2_; ++k)
            st[tx * 52 + k * 2 + ty] = __float2half(ex[k]);
    }
    __syncthreads();

    // write: maskT[b][(i*64+j)*100 + k2*4 + s2h*2 + {0,1}] as half2
    __half* mrow = maskT + ((size_t)b * HW_ + i * 64) * 100 + s2h * 2;
    for (int e = tid; e < 1600; e += 512) {
        int j = e / 25;
        int kk = e - j * 25;
        *(__half2*)(mrow + j * 100 + kk * 4) = *(const __half2*)&st[j * 52 + kk * 2];
    }
}

// ---------------------------------------------------------------------------
// Kernel C (v3): persistent double-buffered reassembly + pixel shuffle.
// 512 blocks x 256 thr; block owns fixed row i (XCD gets 8 consecutive i's),
// loops 8 items (b x cc-pair). Staging via global_load_lds into planar LDS
// [r][c][68] (lane-contiguous); halo cols/rows pre-zeroed once, never
// overwritten. Pipeline: issue stage(n+1) -> compute(n) -> vmcnt(0)+barrier.
// LDS 69.1 KB -> 2 blocks/CU; load latency hides under compute.
// ---------------------------------------------------------------------------
__global__ void __launch_bounds__(256)
k_reassemble(const float* __restrict__ x, const __half* __restrict__ maskT,
             float* __restrict__ out) {
    __shared__ float sxp[2][5][16][68];               // 43,520 B
    __shared__ __align__(16) __half smaskp[2][6400];  // 25,600 B
    const int tx = threadIdx.x;                    // j (= lane)
    const int ty = threadIdx.y;                    // wave id / ch-quad
    const int tid = ty * 64 + tx;

    const int bid = blockIdx.x;                    // 0..511
    const int xcd = bid & 7;
    const int kk  = bid >> 3;                      // 0..63
    const int i   = xcd * 8 + (kk & 7);            // 8 consecutive i per XCD
    const int bc  = kk >> 3;                       // 0..7 -> cc pair {2bc, 2bc+1}

    // ---- prologue: zero halo cols {0,1,66,67} in both buffers ----
    for (int e = tid; e < 640; e += 256) {
        int d = e / 320; int rem = e - d * 320;
        int r = rem >> 6; int rem2 = rem & 63;
        int c = rem2 >> 2; int q = rem2 & 3;
        int col = (q & 1) + (q >> 1) * 66;         // 0,1,66,67
        sxp[d][r][c][col] = 0.f;
    }
    // ---- zero out-of-image row planes (constant per block since i fixed) ----
#pragma unroll
    for (int r = 0; r < 5; ++r) {
        int gi = i + r - 2;
        if ((unsigned)gi >= 64u) {
            for (int e = tid; e < 2 * 16 * 68; e += 256) {
                int d = e / 1088; int rem = e - d * 1088;
                int c = rem / 68; int col = rem - c * 68;
                sxp[d][r][c][col] = 0.f;
            }
        }
    }

    auto stage = [&](int n, int d) {
        const int b  = n >> 1;
        const int cc = bc * 2 + (n & 1);
        const float* xit = x + ((size_t)b * C_ + cc * 16) * HW_;
#pragma unroll
        for (int r = 0; r < 5; ++r) {
            int gi = i + r - 2;
            if ((unsigned)gi < 64u) {              // uniform branch
#pragma unroll
                for (int c4 = 0; c4 < 4; ++c4) {
                    int c = (ty << 2) + c4;        // wave-uniform
                    gload4(xit + (size_t)c * HW_ + gi * W_ + tx, &sxp[d][r][c][2]);
                }
            }
        }
        // mask row: 12800 B = 12 x 1KB (width16) + 2 x 256B (width4)
        const char* mrow = (const char*)(maskT + ((size_t)b * HW_ + i * 64) * 100);
        char* mdst = (char*)&smaskp[d][0];
        if (ty < 3) {
#pragma unroll
            for (int m = 0; m < 4; ++m) {
                int mi = ty * 4 + m;
                gload16(mrow + mi * 1024 + tx * 16, mdst + mi * 1024);
            }
        } else {
            gload4(mrow + 12288 + tx * 4, mdst + 12288);
            gload4(mrow + 12544 + tx * 4, mdst + 12544);
        }
    };

    stage(0, 0);

#pragma unroll 1
    for (int n = 0; n < 8; ++n) {
        const int d = n & 1;
        asm volatile("s_waitcnt vmcnt(0)" ::: "memory");  // stage(n) landed
        __syncthreads();
        if (n + 1 < 8) stage(n + 1, d ^ 1);               // flies under compute(n)

        const int b  = n >> 1;
        const int cc = bc * 2 + (n & 1);

        v2f a01[4], a23[4];
#pragma unroll
        for (int cl = 0; cl < 4; ++cl) { a01[cl] = (v2f){0.f, 0.f}; a23[cl] = (v2f){0.f, 0.f}; }

#pragma unroll
        for (int k2 = 0; k2 < K2_; ++k2) {
            const int dy = k2 / 5, dx = k2 % 5;
            __half2 h01 = *(const __half2*)&smaskp[d][tx * 100 + k2 * 4];
            __half2 h23 = *(const __half2*)&smaskp[d][tx * 100 + k2 * 4 + 2];
            float2 f01 = __half22float2(h01);
            float2 f23 = __half22float2(h23);
            v2f m01 = (v2f){f01.x, f01.y};
            v2f m23 = (v2f){f23.x, f23.y};
#pragma unroll
            for (int cl = 0; cl < 4; ++cl) {
                float xv = sxp[d][dy][(ty << 2) + cl][tx + dx];
                v2f xv2 = (v2f){xv, xv};
                a01[cl] = FMA2(xv2, m01, a01[cl]);
                a23[cl] = FMA2(xv2, m23, a23[cl]);
            }
        }

#pragma unroll
        for (int cl = 0; cl < 4; ++cl) {
            int c = cc * 16 + (ty << 2) + cl;
            float* op = out + (((size_t)(b * C_ + c) * 128 + 2 * i) * 128) + 2 * tx;
            *(float2*)op         = float2{a01[cl].x, a01[cl].y};
            *(float2*)(op + 128) = float2{a23[cl].x, a23[cl].y};
        }
    }
}

// ---------------------------------------------------------------------------
extern "C" void kernel_launch(void* const* d_in, const int* in_sizes, int n_in,
                              void* d_out, int out_size, void* d_ws, size_t ws_size,
                              hipStream_t stream) {
    const float* x       = (const float*)d_in[0];
    const float* w_comp  = (const float*)d_in[1];
    const float* bn_g    = (const float*)d_in[2];
    const float* bn_b    = (const float*)d_in[3];
    const float* bn_m    = (const float*)d_in[4];
    const float* bn_v    = (const float*)d_in[5];
    const float* w_enc   = (const float*)d_in[6];
    float* out = (float*)d_out;

    float* ws    = (float*)d_ws;
    float* wTc   = ws;                               // 16384 floats
    float* wTe   = ws + 16384;                       // 59904 floats (stride 26)
    float* act   = ws + 16384 + 59904;               // 1,048,576 floats
    __half* maskT = (__half*)(act + (size_t)B_ * COMP_ * HW_);  // 1,638,400 halfs

    k_transpose<<<289, 256, 0, stream>>>(w_comp, w_enc, wTc, wTe);
    k_compress<<<dim3(64, B_), dim3(64, 8), 0, stream>>>(x, wTc, bn_g, bn_b, bn_m, bn_v, act);
    k_encoder<<<dim3(64, B_, 2), dim3(64, 2, 4), 0, stream>>>(act, wTe, maskT);
    k_reassemble<<<512, dim3(64, 4), 0, stream>>>(x, maskT, out);
}

// Round 4
// 147.174 us; speedup vs baseline: 1.1558x; 1.1558x over previous
//
#include <hip/hip_runtime.h>
#include <hip/hip_bf16.h>
#include <hip/hip_fp16.h>
#include <math.h>

// Problem constants
#define B_ 4
#define C_ 256
#define H_ 64
#define W_ 64
#define COMP_ 64
#define K2_ 25
#define HW_ (H_*W_)   // 4096
#define EPS_ 1e-5f

typedef float v2f __attribute__((ext_vector_type(2)));
typedef float f32x4 __attribute__((ext_vector_type(4)));
typedef _Float16 half8 __attribute__((ext_vector_type(8)));
#define FMA2(a, b, c) __builtin_elementwise_fma((a), (b), (c))

// ---------------------------------------------------------------------------
// Kernel T: weight layout transforms.
//   wTc[c*64+o] = w_comp[o*256+c]                       (compress weights)
//   Apack: MFMA A-fragments for the encoder GEMM, fp16.
//     slot t2 = (MT*18 + ks)*64 + lane, 8 halfs each:
//     e -> W[m = MT*16 + (lane&15)][k = ks*32 + (lane>>4)*8 + e]
//     with k = q*64 + c (q = 3x3 tap, c = in-channel), W[m][k] =
//     w_enc[(m*64 + c)*9 + q], zero-padded for m >= 100 (M padded to 128).
// ---------------------------------------------------------------------------
__global__ void k_transpose(const float* __restrict__ w_comp,
                            const float* __restrict__ w_enc,
                            float* __restrict__ wTc,
                            __half* __restrict__ Apack) {
    int t = blockIdx.x * 256 + threadIdx.x;
    if (t < COMP_ * C_) {
        int o = t & 63;
        int c = t >> 6;
        wTc[t] = w_comp[o * C_ + c];
    } else {
        int t2 = t - COMP_ * C_;
        if (t2 < 8 * 18 * 64) {                     // 9216 fragment slots
            int lane = t2 & 63;
            int ks   = (t2 >> 6) % 18;
            int MT   = t2 / (64 * 18);
            int m    = MT * 16 + (lane & 15);
            __half vals[8];
#pragma unroll
            for (int e = 0; e < 8; ++e) {
                int k = ks * 32 + (lane >> 4) * 8 + e;
                int q = k >> 6;                     // 0..8 (ky*3+kx)
                int c = k & 63;
                float wv = (m < 100) ? w_enc[(m * COMP_ + c) * 9 + q] : 0.f;
                vals[e] = __float2half(wv);
            }
            *(float4*)&Apack[(size_t)t2 * 8] = *(float4*)vals;
        }
    }
}

// ---------------------------------------------------------------------------
// Kernel A (v3): 1x1 compression (256->64) + BN + SiLU -> fp16 act16[b][px][c].
// Same GEMM body as v2 (measured ~6 us); output repacked px-major fp16 via
// LDS transpose so the encoder can stage channel-contiguous MFMA B-operands.
// ---------------------------------------------------------------------------
__global__ void __launch_bounds__(512)
k_compress(const float* __restrict__ x, const float* __restrict__ wTc,
           const float* __restrict__ gamma, const float* __restrict__ beta,
           const float* __restrict__ mean, const float* __restrict__ var,
           __half* __restrict__ act16) {
    __shared__ float sx[256 * 68];                 // 69,632 B
    const int tx = threadIdx.x;                    // px
    const int ty = threadIdx.y;                    // og (0..7)
    const int tid = ty * 64 + tx;
    const int ogu = __builtin_amdgcn_readfirstlane(ty);
    const int bb = blockIdx.y;
    const int p0 = blockIdx.x * 64;

    const float* xb = x + (size_t)bb * C_ * HW_ + p0;
#pragma unroll
    for (int l = 0; l < 8; ++l) {
        int e = tid + l * 512;                     // 0..4095
        int c = e >> 4;
        int p4 = (e & 15) << 2;
        float4 v4 = *(const float4*)(xb + (size_t)c * HW_ + p4);
        *(float4*)&sx[c * 68 + p4] = v4;
    }
    __syncthreads();

    v2f acc2[4];
#pragma unroll
    for (int k = 0; k < 4; ++k) acc2[k] = (v2f){0.f, 0.f};

#pragma unroll 8
    for (int c = 0; c < 256; ++c) {
        float xv = sx[c * 68 + tx];
        const v2f* w2 = (const v2f*)(wTc + c * COMP_ + ogu * 8);  // uniform -> s_load
        v2f xv2 = (v2f){xv, xv};
#pragma unroll
        for (int k = 0; k < 4; ++k)
            acc2[k] = FMA2(xv2, w2[k], acc2[k]);
    }

    // BN + SiLU -> fp16, repack to px-major via LDS (stride 68 halfs: 2-way banks)
    __half h8[8];
#pragma unroll
    for (int k = 0; k < 4; ++k) {
#pragma unroll
        for (int h = 0; h < 2; ++h) {
            int o = ty * 8 + 2 * k + h;
            float sv = (h == 0) ? acc2[k].x : acc2[k].y;
            float iv = gamma[o] * rsqrtf(var[o] + EPS_);
            float bn = (sv - mean[o]) * iv + beta[o];
            float sg = 1.f / (1.f + __expf(-bn));
            h8[2 * k + h] = __float2half(bn * sg);
        }
    }
    __syncthreads();                               // sx reads done
    __half* sxh = (__half*)sx;                     // [px][68] halfs
    *(float2*)&sxh[tx * 68 + ty * 8]     = *(float2*)&h8[0];
    *(float2*)&sxh[tx * 68 + ty * 8 + 4] = *(float2*)&h8[4];
    __syncthreads();

    // coalesced copy-out: 512 x 16B, dst fully contiguous 8 KB
    {
        int px = tid >> 3, c8 = tid & 7;
        float2 alo = *(float2*)&sxh[px * 68 + c8 * 8];
        float2 ahi = *(float2*)&sxh[px * 68 + c8 * 8 + 4];
        float4 v = make_float4(alo.x, alo.y, ahi.x, ahi.y);
        __half* ao = act16 + ((size_t)bb * HW_ + p0 + px) * COMP_ + c8 * 8;
        *(float4*)ao = v;
    }
}

// ---------------------------------------------------------------------------
// Kernel B (v3.1): encoder conv as implicit MFMA GEMM + softmax(25) + fp16 out.
// Per (b,i): mask[112pad][64px] = W[112][576] x im2col(act16)[576][64px].
// Block 512 thr = 8 waves: wave = (n-tile j0 = (w&3)*16, m-half = (w>>2)*64).
// B-frags: ds_read_b128 from sact[3 rows][66 cols][c pad80] fp16.
// FIX vs v3: im2col column slot is j0+p+kx (global col j+kx-1 stored at
// slot col+1) — v3's extra +1 shifted taps and read past sact (NaN).
// A-frags: global half8 loads of Apack (147 KB, L2-hot). 72 MFMAs/wave.
// C layout (HW-verified): col=lane&15=px, row=(lane>>4)*4+reg=m.
// ---------------------------------------------------------------------------
__global__ void __launch_bounds__(512)
k_encoder(const __half* __restrict__ act16, const __half* __restrict__ Apack,
          __half* __restrict__ maskT) {
    __shared__ __align__(16) __half sact[3 * 66 * 80];   // 31,680 B
    __shared__ float cbuf[64 * 129];                      // 33,024 B
    __shared__ __align__(16) __half st[64 * 100];         // 12,800 B
    const int tid = threadIdx.x;
    const int i = blockIdx.x, b = blockIdx.y;
    const int lane = tid & 63, w = tid >> 6;

    // ---- stage act rows i-1..i+1 (fp16, channel-contiguous, zero halos) ----
    const __half* ab = act16 + (size_t)b * HW_ * COMP_;
    {
        int col = tid >> 3, c8 = tid & 7;
#pragma unroll
        for (int r = 0; r < 3; ++r) {
            int gi = i + r - 1;                    // uniform per r
            float4 v = make_float4(0.f, 0.f, 0.f, 0.f);
            if ((unsigned)gi < 64u)
                v = *(const float4*)(ab + ((size_t)gi * 64 + col) * COMP_ + c8 * 8);
            *(float4*)((char*)sact + (size_t)(r * 66 + col + 1) * 160 + c8 * 16) = v;
        }
    }
    if (tid < 60) {                                // halo cols 0 and 65, 3 rows
        int pl = tid / 10, sl = tid % 10;
        int r = pl >> 1, col = (pl & 1) * 65;
        *(float4*)((char*)sact + (size_t)(r * 66 + col) * 160 + sl * 16) =
            make_float4(0.f, 0.f, 0.f, 0.f);
    }
    __syncthreads();

    // ---- MFMA main loop: 18 k-steps (k = q*64 + c), 4 m-tiles per wave ----
    const int j0 = (w & 3) * 16;
    const int MT0 = (w >> 2) * 4;
    const int p = lane & 15, g = lane >> 4;
    f32x4 acc[4];
#pragma unroll
    for (int mt = 0; mt < 4; ++mt) acc[mt] = (f32x4){0.f, 0.f, 0.f, 0.f};
    const half8* Ap = (const half8*)Apack;
#pragma unroll
    for (int ks = 0; ks < 18; ++ks) {
        const int q = ks >> 1, ky = q / 3, kx = q % 3;      // compile-time
        half8 bf = *(const half8*)((const char*)sact +
                       (size_t)(ky * 66 + j0 + p + kx) * 160 +
                       ((ks & 1) * 32 + g * 8) * 2);
#pragma unroll
        for (int mt = 0; mt < 4; ++mt) {
            half8 af = Ap[((size_t)(MT0 + mt) * 18 + ks) * 64 + lane];
            acc[mt] = __builtin_amdgcn_mfma_f32_16x16x32_f16(af, bf, acc[mt], 0, 0, 0);
        }
    }

    // ---- C -> LDS transpose buffer [px][m pad129] ----
#pragma unroll
    for (int mt = 0; mt < 4; ++mt)
#pragma unroll
        for (int r4 = 0; r4 < 4; ++r4)
            cbuf[(j0 + p) * 129 + (MT0 + mt) * 16 + g * 4 + r4] = acc[mt][r4];
    __syncthreads();

    // ---- softmax over 25 taps (m = k2*4 + s2), 256 threads ----
    if (tid < 256) {
        int px = tid & 63, s2 = tid >> 6;
        float v[K2_];
        float mx = -1e30f;
#pragma unroll
        for (int k2 = 0; k2 < K2_; ++k2) {
            v[k2] = cbuf[px * 129 + k2 * 4 + s2];
            mx = fmaxf(mx, v[k2]);
        }
        float sum = 0.f;
#pragma unroll
        for (int k2 = 0; k2 < K2_; ++k2) { v[k2] = __expf(v[k2] - mx); sum += v[k2]; }
        float rs = 1.f / sum;
#pragma unroll
        for (int k2 = 0; k2 < K2_; ++k2)
            st[px * 100 + k2 * 4 + s2] = __float2half(v[k2] * rs);
    }
    __syncthreads();

    // ---- coalesced write: maskT[b][(i*64+j)*100 + ch], 800 float4 of halfs ----
    float4* dst = (float4*)(maskT + ((size_t)b * HW_ + i * 64) * 100);
    const float4* src = (const float4*)st;
    for (int e = tid; e < 800; e += 512) dst[e] = src[e];
}

// ---------------------------------------------------------------------------
// Kernel C (v4 = R0 body, measured 44.7us, + bijective XCD swizzle ONLY).
// id = ((b*64+i)*16+cc); each XCD gets 512 consecutive ids -> 16 cc-blocks of
// one (b,i) share its mask row + x halo in one L2; consecutive i reuse rows.
// ---------------------------------------------------------------------------
__global__ void __launch_bounds__(256)
k_reassemble(const float* __restrict__ x, const __half* __restrict__ maskT,
             float* __restrict__ out) {
    __shared__ __align__(16) __half smask[64 * 100];  // 12.8 KB
    __shared__ __align__(16) float sx[5 * 68 * 20];   // 27.2 KB
    const int tx = threadIdx.x;                    // j
    const int ty = threadIdx.y;                    // ch-quad
    const int tid = ty * 64 + tx;

    const int bid = blockIdx.x;                    // 0..4095
    const int id  = ((bid & 7) << 9) | (bid >> 3); // bijective XCD swizzle
    const int cc = id & 15;
    const int i  = (id >> 4) & 63;
    const int b  = id >> 10;

    // ---- mask row: fully coalesced float4 copy (800 float4 of halfs) ----
    {
        const float4* src = (const float4*)(maskT + ((size_t)b * HW_ + i * 64) * 100);
        float4* dst = (float4*)smask;
#pragma unroll
        for (int t = 0; t < 4; ++t) {
            int e = tid + t * 256;
            if (e < 800) dst[e] = src[e];
        }
    }

    // ---- x tile: per-thread float4 of 4 channels -> ds_write_b128 ----
    const float* xb = x + ((size_t)b * C_ + cc * 16 + ty * 4) * HW_;
#pragma unroll
    for (int r = 0; r < 5; ++r) {
        const int gi = i + r - 2;                  // uniform
        const bool rowok = ((unsigned)gi < 64u);   // uniform branch
        {
            float4 v = {0.f, 0.f, 0.f, 0.f};
            int gj = tx - 2;
            if (rowok && gj >= 0) {                // gj <= 61 always
                const float* p = xb + gi * W_ + gj;
                v.x = p[0];
                v.y = p[HW_];
                v.z = p[2 * HW_];
                v.w = p[3 * HW_];
            }
            *(float4*)&sx[(r * 68 + tx) * 20 + ty * 4] = v;
        }
        if (tid < 16) {                            // tail cols 64..67
            int q = tid >> 2;
            int col = 64 + (tid & 3);
            int gj = col - 2;                      // 62..65
            float4 v = {0.f, 0.f, 0.f, 0.f};
            if (rowok && gj < 64) {
                const float* p = x + ((size_t)b * C_ + cc * 16 + q * 4) * HW_ + gi * W_ + gj;
                v.x = p[0];
                v.y = p[HW_];
                v.z = p[2 * HW_];
                v.w = p[3 * HW_];
            }
            *(float4*)&sx[(r * 68 + col) * 20 + q * 4] = v;
        }
    }
    __syncthreads();

    v2f a01[4], a23[4];
#pragma unroll
    for (int cl = 0; cl < 4; ++cl) { a01[cl] = (v2f){0.f, 0.f}; a23[cl] = (v2f){0.f, 0.f}; }

    // prefetch k2=0
    float4 xq = *(const float4*)&sx[(0 * 68 + tx + 0) * 20 + ty * 4];
    __half2 h01 = *(const __half2*)&smask[tx * 100 + 0];
    __half2 h23 = *(const __half2*)&smask[tx * 100 + 2];

#pragma unroll
    for (int k2 = 0; k2 < K2_; ++k2) {
        float4 xq_c = xq;
        __half2 h01_c = h01, h23_c = h23;
        if (k2 < K2_ - 1) {
            const int kn = k2 + 1;
            const int dy = kn / 5, dx = kn % 5;
            xq  = *(const float4*)&sx[(dy * 68 + tx + dx) * 20 + ty * 4];
            h01 = *(const __half2*)&smask[tx * 100 + kn * 4];
            h23 = *(const __half2*)&smask[tx * 100 + kn * 4 + 2];
        }
        float2 f01 = __half22float2(h01_c);
        float2 f23 = __half22float2(h23_c);
        v2f m01 = (v2f){f01.x, f01.y};
        v2f m23 = (v2f){f23.x, f23.y};
        float xc[4] = {xq_c.x, xq_c.y, xq_c.z, xq_c.w};
#pragma unroll
        for (int cl = 0; cl < 4; ++cl) {
            v2f xv2 = (v2f){xc[cl], xc[cl]};
            a01[cl] = FMA2(xv2, m01, a01[cl]);
            a23[cl] = FMA2(xv2, m23, a23[cl]);
        }
    }

#pragma unroll
    for (int cl = 0; cl < 4; ++cl) {
        int c = cc * 16 + ty * 4 + cl;
        float* op = out + (((size_t)(b * C_ + c) * 128 + 2 * i) * 128) + 2 * tx;
        *(float2*)op         = float2{a01[cl].x, a01[cl].y};
        *(float2*)(op + 128) = float2{a23[cl].x, a23[cl].y};
    }
}

// ---------------------------------------------------------------------------
extern "C" void kernel_launch(void* const* d_in, const int* in_sizes, int n_in,
                              void* d_out, int out_size, void* d_ws, size_t ws_size,
                              hipStream_t stream) {
    const float* x       = (const float*)d_in[0];
    const float* w_comp  = (const float*)d_in[1];
    const float* bn_g    = (const float*)d_in[2];
    const float* bn_b    = (const float*)d_in[3];
    const float* bn_m    = (const float*)d_in[4];
    const float* bn_v    = (const float*)d_in[5];
    const float* w_enc   = (const float*)d_in[6];
    float* out = (float*)d_out;

    float* ws     = (float*)d_ws;
    float* wTc    = ws;                              // 16,384 floats
    __half* Apack = (__half*)(ws + 16384);           // 73,728 halfs
    __half* act16 = (__half*)(ws + 53248);           // 1,048,576 halfs
    __half* maskT = (__half*)(ws + 577536);          // 1,638,400 halfs

    k_transpose<<<100, 256, 0, stream>>>(w_comp, w_enc, wTc, Apack);
    k_compress<<<dim3(64, B_), dim3(64, 8), 0, stream>>>(x, wTc, bn_g, bn_b, bn_m, bn_v, act16);
    k_encoder<<<dim3(64, B_), 512, 0, stream>>>(act16, Apack, maskT);
    k_reassemble<<<4096, dim3(64, 4), 0, stream>>>(x, maskT, out);
}

// Round 5
// 147.032 us; speedup vs baseline: 1.1569x; 1.0010x over previous
//
#include <hip/hip_runtime.h>
#include <hip/hip_bf16.h>
#include <hip/hip_fp16.h>
#include <math.h>

// Problem constants
#define B_ 4
#define C_ 256
#define H_ 64
#define W_ 64
#define COMP_ 64
#define K2_ 25
#define HW_ (H_*W_)   // 4096
#define EPS_ 1e-5f

typedef float v2f __attribute__((ext_vector_type(2)));
typedef float f32x4 __attribute__((ext_vector_type(4)));
typedef _Float16 half8 __attribute__((ext_vector_type(8)));
#define FMA2(a, b, c) __builtin_elementwise_fma((a), (b), (c))

// ---------------------------------------------------------------------------
// Kernel T: weight layout transforms.
//   wTc[c*64+o] = w_comp[o*256+c]                       (compress weights)
//   Apack: MFMA A-fragments for the encoder GEMM, fp16.
//     slot t2 = (MT*18 + ks)*64 + lane, 8 halfs each:
//     e -> W[m = MT*16 + (lane&15)][k = ks*32 + (lane>>4)*8 + e]
//     with k = q*64 + c (q = 3x3 tap, c = in-channel), W[m][k] =
//     w_enc[(m*64 + c)*9 + q], zero-padded for m >= 100 (M padded to 128).
// ---------------------------------------------------------------------------
__global__ void k_transpose(const float* __restrict__ w_comp,
                            const float* __restrict__ w_enc,
                            float* __restrict__ wTc,
                            __half* __restrict__ Apack) {
    int t = blockIdx.x * 256 + threadIdx.x;
    if (t < COMP_ * C_) {
        int o = t & 63;
        int c = t >> 6;
        wTc[t] = w_comp[o * C_ + c];
    } else {
        int t2 = t - COMP_ * C_;
        if (t2 < 8 * 18 * 64) {                     // 9216 fragment slots
            int lane = t2 & 63;
            int ks   = (t2 >> 6) % 18;
            int MT   = t2 / (64 * 18);
            int m    = MT * 16 + (lane & 15);
            __half vals[8];
#pragma unroll
            for (int e = 0; e < 8; ++e) {
                int k = ks * 32 + (lane >> 4) * 8 + e;
                int q = k >> 6;                     // 0..8 (ky*3+kx)
                int c = k & 63;
                float wv = (m < 100) ? w_enc[(m * COMP_ + c) * 9 + q] : 0.f;
                vals[e] = __float2half(wv);
            }
            *(float4*)&Apack[(size_t)t2 * 8] = *(float4*)vals;
        }
    }
}

// ---------------------------------------------------------------------------
// Kernel A (v3, unchanged): 1x1 compression + BN + SiLU -> fp16 act16[b][px][c].
// ---------------------------------------------------------------------------
__global__ void __launch_bounds__(512)
k_compress(const float* __restrict__ x, const float* __restrict__ wTc,
           const float* __restrict__ gamma, const float* __restrict__ beta,
           const float* __restrict__ mean, const float* __restrict__ var,
           __half* __restrict__ act16) {
    __shared__ float sx[256 * 68];                 // 69,632 B
    const int tx = threadIdx.x;                    // px
    const int ty = threadIdx.y;                    // og (0..7)
    const int tid = ty * 64 + tx;
    const int ogu = __builtin_amdgcn_readfirstlane(ty);
    const int bb = blockIdx.y;
    const int p0 = blockIdx.x * 64;

    const float* xb = x + (size_t)bb * C_ * HW_ + p0;
#pragma unroll
    for (int l = 0; l < 8; ++l) {
        int e = tid + l * 512;                     // 0..4095
        int c = e >> 4;
        int p4 = (e & 15) << 2;
        float4 v4 = *(const float4*)(xb + (size_t)c * HW_ + p4);
        *(float4*)&sx[c * 68 + p4] = v4;
    }
    __syncthreads();

    v2f acc2[4];
#pragma unroll
    for (int k = 0; k < 4; ++k) acc2[k] = (v2f){0.f, 0.f};

#pragma unroll 8
    for (int c = 0; c < 256; ++c) {
        float xv = sx[c * 68 + tx];
        const v2f* w2 = (const v2f*)(wTc + c * COMP_ + ogu * 8);  // uniform -> s_load
        v2f xv2 = (v2f){xv, xv};
#pragma unroll
        for (int k = 0; k < 4; ++k)
            acc2[k] = FMA2(xv2, w2[k], acc2[k]);
    }

    // BN + SiLU -> fp16, repack to px-major via LDS (stride 68 halfs: 2-way banks)
    __half h8[8];
#pragma unroll
    for (int k = 0; k < 4; ++k) {
#pragma unroll
        for (int h = 0; h < 2; ++h) {
            int o = ty * 8 + 2 * k + h;
            float sv = (h == 0) ? acc2[k].x : acc2[k].y;
            float iv = gamma[o] * rsqrtf(var[o] + EPS_);
            float bn = (sv - mean[o]) * iv + beta[o];
            float sg = 1.f / (1.f + __expf(-bn));
            h8[2 * k + h] = __float2half(bn * sg);
        }
    }
    __syncthreads();                               // sx reads done
    __half* sxh = (__half*)sx;                     // [px][68] halfs
    *(float2*)&sxh[tx * 68 + ty * 8]     = *(float2*)&h8[0];
    *(float2*)&sxh[tx * 68 + ty * 8 + 4] = *(float2*)&h8[4];
    __syncthreads();

    // coalesced copy-out: 512 x 16B, dst fully contiguous 8 KB
    {
        int px = tid >> 3, c8 = tid & 7;
        float2 alo = *(float2*)&sxh[px * 68 + c8 * 8];
        float2 ahi = *(float2*)&sxh[px * 68 + c8 * 8 + 4];
        float4 v = make_float4(alo.x, alo.y, ahi.x, ahi.y);
        __half* ao = act16 + ((size_t)bb * HW_ + p0 + px) * COMP_ + c8 * 8;
        *(float4*)ao = v;
    }
}

// ---------------------------------------------------------------------------
// Kernel B (v4): MFMA encoder, j split across grid for occupancy.
// grid (64 i, 4 b, 2 jh) = 512 blocks (was 256 = 1/CU, fully latency-exposed).
// Block 512 thr = 8 waves: wave = (j-sub jloc0=(w&1)*16, m-pair MT0=(w>>1)*2).
// 36 MFMA/wave. LDS 39.2 KB -> 2 blocks/CU resident, 16 waves/CU.
// Same math as v3.1 (bit-identical); slot s <-> global col jh*32 + s - 1.
// ---------------------------------------------------------------------------
__global__ void __launch_bounds__(512)
k_encoder(const __half* __restrict__ act16, const __half* __restrict__ Apack,
          __half* __restrict__ maskT) {
    __shared__ __align__(16) __half sact[3 * 34 * 80];   // 16,320 B (160 B/slot)
    __shared__ float cbuf[32 * 129];                      // 16,512 B
    __shared__ __align__(16) __half st[32 * 100];         // 6,400 B
    const int tid = threadIdx.x;
    const int i = blockIdx.x, b = blockIdx.y, jh = blockIdx.z;
    const int lane = tid & 63, w = tid >> 6;

    // ---- stage act rows i-1..i+1, col slots 0..33 (gj = jh*32 + s - 1) ----
    const __half* ab = act16 + (size_t)b * HW_ * COMP_;
    for (int t = tid; t < 3 * 34 * 8; t += 512) {
        int c8 = t & 7;
        int s  = (t >> 3) % 34;
        int r  = t / (34 * 8);
        int gi = i + r - 1;
        int gj = jh * 32 + s - 1;
        float4 v = make_float4(0.f, 0.f, 0.f, 0.f);
        if ((unsigned)gi < 64u && (unsigned)gj < 64u)
            v = *(const float4*)(ab + ((size_t)gi * 64 + gj) * COMP_ + c8 * 8);
        *(float4*)((char*)sact + (size_t)(r * 34 + s) * 160 + c8 * 16) = v;
    }
    __syncthreads();

    // ---- MFMA: 18 k-steps x 2 m-tiles per wave ----
    const int jloc0 = (w & 1) * 16;
    const int MT0   = (w >> 1) * 2;
    const int p = lane & 15, g = lane >> 4;
    f32x4 acc[2];
#pragma unroll
    for (int mt = 0; mt < 2; ++mt) acc[mt] = (f32x4){0.f, 0.f, 0.f, 0.f};
    const half8* Ap = (const half8*)Apack;
#pragma unroll
    for (int ks = 0; ks < 18; ++ks) {
        const int q = ks >> 1, ky = q / 3, kx = q % 3;      // compile-time
        half8 bf = *(const half8*)((const char*)sact +
                       (size_t)(ky * 34 + jloc0 + p + kx) * 160 +
                       ((ks & 1) * 32 + g * 8) * 2);
#pragma unroll
        for (int mt = 0; mt < 2; ++mt) {
            half8 af = Ap[((size_t)(MT0 + mt) * 18 + ks) * 64 + lane];
            acc[mt] = __builtin_amdgcn_mfma_f32_16x16x32_f16(af, bf, acc[mt], 0, 0, 0);
        }
    }

    // ---- C -> LDS transpose buffer [px 0..31][m pad129] ----
#pragma unroll
    for (int mt = 0; mt < 2; ++mt)
#pragma unroll
        for (int r4 = 0; r4 < 4; ++r4)
            cbuf[(jloc0 + p) * 129 + (MT0 + mt) * 16 + g * 4 + r4] = acc[mt][r4];
    __syncthreads();

    // ---- softmax over 25 taps (m = k2*4 + s2), 128 threads ----
    if (tid < 128) {
        int px = tid & 31, s2 = tid >> 5;
        float v[K2_];
        float mx = -1e30f;
#pragma unroll
        for (int k2 = 0; k2 < K2_; ++k2) {
            v[k2] = cbuf[px * 129 + k2 * 4 + s2];
            mx = fmaxf(mx, v[k2]);
        }
        float sum = 0.f;
#pragma unroll
        for (int k2 = 0; k2 < K2_; ++k2) { v[k2] = __expf(v[k2] - mx); sum += v[k2]; }
        float rs = 1.f / sum;
#pragma unroll
        for (int k2 = 0; k2 < K2_; ++k2)
            st[px * 100 + k2 * 4 + s2] = __float2half(v[k2] * rs);
    }
    __syncthreads();

    // ---- coalesced write: 32 px x 100 ch = 400 float4 of halfs ----
    float4* dst = (float4*)(maskT + ((size_t)b * HW_ + i * 64 + jh * 32) * 100);
    const float4* src = (const float4*)st;
    if (tid < 400) dst[tid] = src[tid];
}

// ---------------------------------------------------------------------------
// Kernel C (v4.1): R0 body + bijective XCD swizzle + b64 mask reads.
// Mask h01/h23 merged into one 8B ds_read_b64 (bit-identical values).
// ---------------------------------------------------------------------------
__global__ void __launch_bounds__(256)
k_reassemble(const float* __restrict__ x, const __half* __restrict__ maskT,
             float* __restrict__ out) {
    __shared__ __align__(16) __half smask[64 * 100];  // 12.8 KB
    __shared__ __align__(16) float sx[5 * 68 * 20];   // 27.2 KB
    const int tx = threadIdx.x;                    // j
    const int ty = threadIdx.y;                    // ch-quad
    const int tid = ty * 64 + tx;

    const int bid = blockIdx.x;                    // 0..4095
    const int id  = ((bid & 7) << 9) | (bid >> 3); // bijective XCD swizzle
    const int cc = id & 15;
    const int i  = (id >> 4) & 63;
    const int b  = id >> 10;

    // ---- mask row: fully coalesced float4 copy (800 float4 of halfs) ----
    {
        const float4* src = (const float4*)(maskT + ((size_t)b * HW_ + i * 64) * 100);
        float4* dst = (float4*)smask;
#pragma unroll
        for (int t = 0; t < 4; ++t) {
            int e = tid + t * 256;
            if (e < 800) dst[e] = src[e];
        }
    }

    // ---- x tile: per-thread float4 of 4 channels -> ds_write_b128 ----
    const float* xb = x + ((size_t)b * C_ + cc * 16 + ty * 4) * HW_;
#pragma unroll
    for (int r = 0; r < 5; ++r) {
        const int gi = i + r - 2;                  // uniform
        const bool rowok = ((unsigned)gi < 64u);   // uniform branch
        {
            float4 v = {0.f, 0.f, 0.f, 0.f};
            int gj = tx - 2;
            if (rowok && gj >= 0) {                // gj <= 61 always
                const float* p = xb + gi * W_ + gj;
                v.x = p[0];
                v.y = p[HW_];
                v.z = p[2 * HW_];
                v.w = p[3 * HW_];
            }
            *(float4*)&sx[(r * 68 + tx) * 20 + ty * 4] = v;
        }
        if (tid < 16) {                            // tail cols 64..67
            int q = tid >> 2;
            int col = 64 + (tid & 3);
            int gj = col - 2;                      // 62..65
            float4 v = {0.f, 0.f, 0.f, 0.f};
            if (rowok && gj < 64) {
                const float* p = x + ((size_t)b * C_ + cc * 16 + q * 4) * HW_ + gi * W_ + gj;
                v.x = p[0];
                v.y = p[HW_];
                v.z = p[2 * HW_];
                v.w = p[3 * HW_];
            }
            *(float4*)&sx[(r * 68 + col) * 20 + q * 4] = v;
        }
    }
    __syncthreads();

    v2f a01[4], a23[4];
#pragma unroll
    for (int cl = 0; cl < 4; ++cl) { a01[cl] = (v2f){0.f, 0.f}; a23[cl] = (v2f){0.f, 0.f}; }

    // prefetch k2=0
    float4 xq = *(const float4*)&sx[(0 * 68 + tx + 0) * 20 + ty * 4];
    float2 hm = *(const float2*)&smask[tx * 100 + 0];   // 4 halfs: h01|h23

#pragma unroll
    for (int k2 = 0; k2 < K2_; ++k2) {
        float4 xq_c = xq;
        float2 hm_c = hm;
        if (k2 < K2_ - 1) {
            const int kn = k2 + 1;
            const int dy = kn / 5, dx = kn % 5;
            xq = *(const float4*)&sx[(dy * 68 + tx + dx) * 20 + ty * 4];
            hm = *(const float2*)&smask[tx * 100 + kn * 4];
        }
        __half2 h01_c = ((const __half2*)&hm_c)[0];
        __half2 h23_c = ((const __half2*)&hm_c)[1];
        float2 f01 = __half22float2(h01_c);
        float2 f23 = __half22float2(h23_c);
        v2f m01 = (v2f){f01.x, f01.y};
        v2f m23 = (v2f){f23.x, f23.y};
        float xc[4] = {xq_c.x, xq_c.y, xq_c.z, xq_c.w};
#pragma unroll
        for (int cl = 0; cl < 4; ++cl) {
            v2f xv2 = (v2f){xc[cl], xc[cl]};
            a01[cl] = FMA2(xv2, m01, a01[cl]);
            a23[cl] = FMA2(xv2, m23, a23[cl]);
        }
    }

#pragma unroll
    for (int cl = 0; cl < 4; ++cl) {
        int c = cc * 16 + ty * 4 + cl;
        float* op = out + (((size_t)(b * C_ + c) * 128 + 2 * i) * 128) + 2 * tx;
        *(float2*)op         = float2{a01[cl].x, a01[cl].y};
        *(float2*)(op + 128) = float2{a23[cl].x, a23[cl].y};
    }
}

// ---------------------------------------------------------------------------
extern "C" void kernel_launch(void* const* d_in, const int* in_sizes, int n_in,
                              void* d_out, int out_size, void* d_ws, size_t ws_size,
                              hipStream_t stream) {
    const float* x       = (const float*)d_in[0];
    const float* w_comp  = (const float*)d_in[1];
    const float* bn_g    = (const float*)d_in[2];
    const float* bn_b    = (const float*)d_in[3];
    const float* bn_m    = (const float*)d_in[4];
    const float* bn_v    = (const float*)d_in[5];
    const float* w_enc   = (const float*)d_in[6];
    float* out = (float*)d_out;

    float* ws     = (float*)d_ws;
    float* wTc    = ws;                              // 16,384 floats
    __half* Apack = (__half*)(ws + 16384);           // 73,728 halfs
    __half* act16 = (__half*)(ws + 53248);           // 1,048,576 halfs
    __half* maskT = (__half*)(ws + 577536);          // 1,638,400 halfs

    k_transpose<<<100, 256, 0, stream>>>(w_comp, w_enc, wTc, Apack);
    k_compress<<<dim3(64, B_), dim3(64, 8), 0, stream>>>(x, wTc, bn_g, bn_b, bn_m, bn_v, act16);
    k_encoder<<<dim3(64, B_, 2), 512, 0, stream>>>(act16, Apack, maskT);
    k_reassemble<<<4096, dim3(64, 4), 0, stream>>>(x, maskT, out);
}